// Round 4
// baseline (80.854 us; speedup 1.0000x reference)
//
#include <hip/hip_runtime.h>

#define NBINS 10001
#define ROWP  10016          // padded row stride in u32 (64B-aligned rows)
#define HIST_BLOCKS 768      // 3 blocks/CU on 256 CUs -> one generation
#define HIST_THREADS 512
#define PCHUNK 128           // partial rows per reduce block

typedef unsigned int u32;
typedef unsigned long long u64;
typedef float f4 __attribute__((ext_vector_type(4)));

__device__ __forceinline__ f4 ntload(const f4* p) {
    return __builtin_nontemporal_load(p);
}

__device__ __forceinline__ int ks_bin(float x) {
    // sigmoid via v_exp + v_rcp (approx rcp ~1ulp; bin perturbation ~1e-7)
    float e = __expf(-x);
    float s = __builtin_amdgcn_rcpf(1.0f + e);
    int b = (int)(10000.0f * s);
    b = b < 0 ? 0 : b;
    return b > 10000 ? 10000 : b;
}

__device__ __forceinline__ void ks_acc4(u32* lh, f4 p, f4 t) {
#pragma unroll
    for (int k = 0; k < 4; ++k) {
        int b = ks_bin(p[k]);
        u32 add = (t[k] >= 0.5f) ? 0x10000u : 1u;
        atomicAdd(&lh[b], add);
    }
}

// ---------------------------------------------------------------------------
// Kernel 1: per-block LDS histogram (packed u32: tp<<16 | fp).
// Per block at most 45056 elements -> 16-bit packed counts cannot overflow.
// 4-way unrolled body: 8 interleaved nontemporal 16B loads issued before any
// use -> ~4-8KB outstanding per wave for latency hiding.
// ---------------------------------------------------------------------------
__global__ __launch_bounds__(HIST_THREADS) void ks_hist(
        const float* __restrict__ preds, const float* __restrict__ tgts,
        u64* __restrict__ ghist, u32* __restrict__ partials,
        int use_partials, int n) {
    __shared__ u32 lh[NBINS];
    for (int i = threadIdx.x; i < NBINS; i += HIST_THREADS) lh[i] = 0u;
    __syncthreads();

    const int n4 = n >> 2;
    const f4* p4 = (const f4*)preds;
    const f4* t4 = (const f4*)tgts;
    const int tid = blockIdx.x * HIST_THREADS + threadIdx.x;
    const int stride = gridDim.x * HIST_THREADS;

    int i = tid;
    for (; i + 3 * stride < n4; i += 4 * stride) {
        f4 p0 = ntload(p4 + i);
        f4 t0 = ntload(t4 + i);
        f4 p1 = ntload(p4 + i + stride);
        f4 t1 = ntload(t4 + i + stride);
        f4 p2 = ntload(p4 + i + 2 * stride);
        f4 t2 = ntload(t4 + i + 2 * stride);
        f4 p3 = ntload(p4 + i + 3 * stride);
        f4 t3 = ntload(t4 + i + 3 * stride);
        ks_acc4(lh, p0, t0);
        ks_acc4(lh, p1, t1);
        ks_acc4(lh, p2, t2);
        ks_acc4(lh, p3, t3);
    }
    for (; i < n4; i += stride) {
        f4 p = ntload(p4 + i);
        f4 t = ntload(t4 + i);
        ks_acc4(lh, p, t);
    }

    // scalar tail (n % 4), handled once by block 0
    if (blockIdx.x == 0) {
        int base = n4 << 2;
        int rem = n - base;
        if ((int)threadIdx.x < rem) {
            int j = base + threadIdx.x;
            int b = ks_bin(preds[j]);
            u32 add = (tgts[j] >= 0.5f) ? 0x10000u : 1u;
            atomicAdd(&lh[b], add);
        }
    }
    __syncthreads();

    if (use_partials) {
        u32* mypart = partials + (size_t)blockIdx.x * ROWP;
        for (int b = threadIdx.x; b < NBINS; b += HIST_THREADS)
            mypart[b] = lh[b];
    } else {
        for (int b = threadIdx.x; b < NBINS; b += HIST_THREADS) {
            u32 v = lh[b];
            if (v) {
                u64 a = ((u64)(v >> 16) << 32) | (u64)(v & 0xFFFFu);
                atomicAdd(&ghist[b], a);
            }
        }
    }
}

// ---------------------------------------------------------------------------
// Kernel 2: reduce partial histograms. grid = (ceil(NBINS/256), HIST_BLOCKS/PCHUNK).
// Each block sums PCHUNK rows for 256 consecutive bins (coalesced 1KB/iter),
// then one packed-u64 atomic per bin per row-chunk.
// ---------------------------------------------------------------------------
__global__ __launch_bounds__(256) void ks_reduce(const u32* __restrict__ partials,
                                                 u64* __restrict__ ghist) {
    int bin = blockIdx.x * 256 + threadIdx.x;
    if (bin >= NBINS) return;
    const u32* base = partials + (size_t)blockIdx.y * PCHUNK * ROWP + bin;
    u32 tp = 0, fp = 0;
#pragma unroll 4
    for (int k = 0; k < PCHUNK; ++k) {
        u32 v = base[(size_t)k * ROWP];
        tp += v >> 16;
        fp += v & 0xFFFFu;
    }
    atomicAdd(&ghist[bin], ((u64)tp << 32) | (u64)fp);
}

// ---------------------------------------------------------------------------
// Kernel 3: exact integer cumsum over 10001 bins (1 block, 1024 threads,
// 10 bins/thread + Hillis-Steele block scan), KS diff in double, block max.
// ---------------------------------------------------------------------------
__global__ __launch_bounds__(1024) void ks_scan(const u64* __restrict__ ghist,
                                                float* __restrict__ out) {
    __shared__ long long stp[1024];
    __shared__ long long sfp[1024];
    __shared__ double smx[1024];

    const int t = threadIdx.x;
    const int CH = 10;  // 1024*10 >= 10001
    const int lo = t * CH;

    u64 loc[CH];
    long long tps = 0, fps = 0;
#pragma unroll
    for (int k = 0; k < CH; ++k) {
        int i = lo + k;
        u64 v = (i < NBINS) ? ghist[i] : 0ull;
        loc[k] = v;
        tps += (long long)(v >> 32);
        fps += (long long)(v & 0xFFFFFFFFull);
    }
    stp[t] = tps;
    sfp[t] = fps;
    __syncthreads();

    for (int off = 1; off < 1024; off <<= 1) {
        long long a = stp[t], b = sfp[t];
        long long c = 0, d = 0;
        if (t >= off) { c = stp[t - off]; d = sfp[t - off]; }
        __syncthreads();
        stp[t] = a + c;
        sfp[t] = b + d;
        __syncthreads();
    }

    const long long TP = stp[1023];
    const long long FP = sfp[1023];
    const long long etp = stp[t] - tps;  // exclusive prefix
    const long long efp = sfp[t] - fps;

    const double invTP = 1.0 / (double)(TP > 0 ? TP : 1);
    const double invFP = 1.0 / (double)(FP > 0 ? FP : 1);

    double m = 0.0;
    long long tc = etp, fc = efp;
#pragma unroll
    for (int k = 0; k < CH; ++k) {
        u64 v = loc[k];
        tc += (long long)(v >> 32);
        fc += (long long)(v & 0xFFFFFFFFull);
        double d = fabs((double)tc * invTP - (double)fc * invFP);
        m = (d > m) ? d : m;
    }

    smx[t] = m;
    __syncthreads();
    for (int off = 512; off > 0; off >>= 1) {
        if (t < off) smx[t] = smx[t] > smx[t + off] ? smx[t] : smx[t + off];
        __syncthreads();
    }
    if (t == 0) out[0] = (float)smx[0];
}

extern "C" void kernel_launch(void* const* d_in, const int* in_sizes, int n_in,
                              void* d_out, int out_size, void* d_ws, size_t ws_size,
                              hipStream_t stream) {
    const float* preds = (const float*)d_in[0];
    const float* tgts  = (const float*)d_in[1];
    const int n = in_sizes[0];

    // ws layout: [ghist: 10001 u64][pad to 128KB][partials: HIST_BLOCKS x ROWP u32]
    const size_t part_off = 131072;
    const size_t need = part_off + (size_t)HIST_BLOCKS * ROWP * sizeof(u32);
    u64* ghist = (u64*)d_ws;
    u32* partials = (u32*)((char*)d_ws + part_off);
    const int use_partials = (ws_size >= need) ? 1 : 0;

    hipMemsetAsync(d_ws, 0, NBINS * sizeof(u64), stream);

    ks_hist<<<HIST_BLOCKS, HIST_THREADS, 0, stream>>>(preds, tgts, ghist,
                                                      partials, use_partials, n);
    if (use_partials) {
        dim3 rg((NBINS + 255) / 256, HIST_BLOCKS / PCHUNK);
        ks_reduce<<<rg, 256, 0, stream>>>(partials, ghist);
    }
    ks_scan<<<1, 1024, 0, stream>>>(ghist, (float*)d_out);
}